// Round 1
// 916.172 us; speedup vs baseline: 1.0015x; 1.0015x over previous
//
#include <hip/hip_runtime.h>
#include <stdint.h>

#define NT 12             // num tasks
#define NG 16384          // num graphs
#define NCH 75            // float4 chunks per 300-float row
#define ROWS 32           // rows per tile (500000 = 32 * 15625 exactly)
#define THREADS 256       // 4 waves  (was 128/2 waves: 8 waves/CU -> 16 waves/CU)
#define TILE_F4 (ROWS * NCH)                 // 2400 float4 = 38.4 KB
#define FULL_ITERS (TILE_F4 / THREADS)       // 9   (9*256 = 2304)
#define TAIL_ACTIVE (TILE_F4 - FULL_ITERS * THREADS)   // 96

typedef const __attribute__((address_space(1))) uint32_t gas_u32;
typedef __attribute__((address_space(3))) uint32_t las_u32;

// Stage 32 contiguous rows into LDS via async global_load_lds (width=16,
// no VGPR round-trip). Compute mapping: lane covers (row, chunk-eighth):
// r = lane&31, h = 2*wave + (lane>>5) in 0..7, chunks [h*75/8, (h+1)*75/8).
// Fold halves within each wave, 5-step segmented scan over the sorted graph
// ids per 32-row window, one atomicAdd per run per task per wave.
// LDS 38.4 KB -> 4 blocks/CU; 4 waves/block -> 16 waves/CU (2x prev).
__global__ __launch_bounds__(THREADS, 4) void pool_proj_kernel(
    const float4* __restrict__ xv, const int* __restrict__ batch,
    const float4* __restrict__ wv, float* __restrict__ acc,
    float* __restrict__ cnt, int n)
{
    extern __shared__ float4 tile[];   // TILE_F4 float4s

    const int tid = threadIdx.x;
    const int lane = tid & 63;
    const int wvid = tid >> 6;
    const long long base_row = (long long)blockIdx.x * ROWS;
    const long long base_f4 = base_row * NCH;
    const long long total_f4 = (long long)n * NCH;

    if (base_f4 + TILE_F4 <= total_f4) {
        // ---- async stage: LDS dest = wave-uniform base + lane*16 ----
        const float4* gsrc = xv + base_f4;
#pragma unroll
        for (int i = 0; i < FULL_ITERS; ++i) {
            const int seg = i * THREADS + 64 * wvid;   // wave-uniform
            __builtin_amdgcn_global_load_lds(
                (gas_u32*)(gsrc + seg + lane),
                (las_u32*)(tile + seg), 16, 0, 0);
        }
        if (tid < TAIL_ACTIVE) {                        // wave0 full, wave1 half
            const int seg = FULL_ITERS * THREADS + 64 * wvid;
            __builtin_amdgcn_global_load_lds(
                (gas_u32*)(gsrc + seg + lane),
                (las_u32*)(tile + seg), 16, 0, 0);
        }
    } else {
        // guarded fallback (only if n % 32 != 0 — not hit for n=500000)
        for (int q = tid; q < TILE_F4; q += THREADS) {
            long long gq = base_f4 + q;
            tile[q] = (gq < total_f4) ? xv[gq] : make_float4(0.f, 0.f, 0.f, 0.f);
        }
    }
    __syncthreads();

    // ---- compute: r = row, h = chunk-eighth ----
    const int r = lane & 31;
    const int h = (wvid << 1) | (lane >> 5);   // 0..7
    const int cstart = (h * NCH) >> 3;         // balanced: sizes 9,9,10,9,9,10,9,10
    const int cend = ((h + 1) * NCH) >> 3;

    float a[NT];
#pragma unroll
    for (int t = 0; t < NT; ++t) a[t] = 0.0f;

#pragma unroll
    for (int j = 0; j < 10; ++j) {
        const int c = cstart + j;
        if (c < cend) {
            float4 xk = tile[r * NCH + c];
#pragma unroll
            for (int t = 0; t < NT; ++t) {
                float4 w = wv[t * NCH + c];    // L1-resident (14.4 KB)
                a[t] = fmaf(xk.x, w.x,
                       fmaf(xk.y, w.y,
                       fmaf(xk.z, w.z,
                       fmaf(xk.w, w.w, a[t]))));
            }
        }
    }

    // ---- fold chunk-halves: lanes 0..31 get this wave's row partials ----
#pragma unroll
    for (int t = 0; t < NT; ++t) a[t] += __shfl_down(a[t], 32);

    long long grow = base_row + r;
    int g = (lane < 32 && grow < n) ? batch[grow] : (0x40000000 + lane);

    // ---- segmented inclusive scan within the 32-row window ----
#pragma unroll
    for (int off = 1; off < 32; off <<= 1) {
        int gu = __shfl_up(g, off);
        bool add = (r >= off) && (gu == g);
#pragma unroll
        for (int t = 0; t < NT; ++t) {
            float vu = __shfl_up(a[t], off);
            if (add) a[t] += vu;
        }
    }
    int gnext = __shfl_down(g, 1);
    int gprev = __shfl_up(g, 1);
    bool tail = (r == 31) || (gnext != g);
    bool head = (r == 0) || (gprev != g);
    unsigned long long heads = __ballot(head);

    if (lane < 32 && tail && g < NG) {
#pragma unroll
        for (int t = 0; t < NT; ++t)
            atomicAdd(&acc[g * NT + t], a[t]);
        if (wvid == 0) {   // counts once per window
            unsigned long long below = heads & (~0ull >> (63 - lane));
            int run_start = 63 - __builtin_clzll(below);
            atomicAdd(&cnt[g], (float)(lane - run_start + 1));
        }
    }
}

// out[g,t] = acc[g,t] / max(cnt[g],1) + b[t]
__global__ __launch_bounds__(256) void finalize_kernel(
    const float* __restrict__ acc, const float* __restrict__ cnt,
    const float* __restrict__ b, float* __restrict__ out)
{
    int idx = blockIdx.x * 256 + threadIdx.x;
    if (idx >= NG * NT) return;
    int gi = idx / NT;
    int t = idx - gi * NT;
    out[idx] = acc[idx] / fmaxf(cnt[gi], 1.0f) + b[t];
}

extern "C" void kernel_launch(void* const* d_in, const int* in_sizes, int n_in,
                              void* d_out, int out_size, void* d_ws, size_t ws_size,
                              hipStream_t stream) {
    const float* x     = (const float*)d_in[0];
    const int*   batch = (const int*)d_in[1];
    const float* W     = (const float*)d_in[2];
    const float* b     = (const float*)d_in[3];
    float* out = (float*)d_out;

    float* acc = (float*)d_ws;
    float* cnt = acc + (size_t)NG * NT;

    const int n = in_sizes[1];  // 500000 nodes

    hipMemsetAsync(d_ws, 0, ((size_t)NG * NT + NG) * sizeof(float), stream);

    const int nblocks = (n + ROWS - 1) / ROWS;   // 15625
    const size_t lds_bytes = (size_t)TILE_F4 * sizeof(float4);  // 38400
    pool_proj_kernel<<<nblocks, THREADS, lds_bytes, stream>>>(
        (const float4*)x, batch, (const float4*)W, acc, cnt, n);

    finalize_kernel<<<(NG * NT + 255) / 256, 256, 0, stream>>>(acc, cnt, b, out);
}